// Round 8
// baseline (348.642 us; speedup 1.0000x reference)
//
#include <hip/hip_runtime.h>
#include <hip/hip_bf16.h>

// Conv2d NCHW, stride=1, pad=1, N=16, C=8, K=8, H=W=1024, 3x3, fp32 in/out.
// Round 8: same MFMA implicit-GEMM as round 7 (layout verified, absmax 0.031),
// staging restructured: (4w x 8ci) tiles -> 8x dwordx4 loads (whole-tile
// 4-aligned predication), v_cvt_pk_bf16_f32 via __float22bfloat162_rn,
// 4 contiguous ds_write_b128 per tile. 40 scalar loads + 160 VALU/thread
// becomes ~11 dwordx4 + ~45 VALU, one latency exposure instead of 5.

typedef __attribute__((ext_vector_type(8))) short short8;
typedef __attribute__((ext_vector_type(4))) float f32x4;

#define HH 1024
#define WW 1024
#define HW (1024*1024)
#define WB 124          // output cols per block
#define HB 8            // output rows per block
#define SROWS 10        // staged input rows (HB+2)
#define SW 136          // staged w per row: w0-4 .. w0+131 (all 4-aligned)
#define UROW 137        // 16B units per LDS row (136 data + 1 pad)
#define TPR 34          // tiles per row (SW/4)
#define NTILES (SROWS*TPR)   // 340
#define GX 9
#define GY 128          // 1024/HB
#define GZ 16
#define NBLK (GX*GY*GZ) // 18432 = 8 * 2304

__device__ __forceinline__ int pk2(float a, float b) {
    __hip_bfloat162 h = __float22bfloat162_rn(make_float2(a, b));  // v_cvt_pk_bf16_f32
    return *reinterpret_cast<int*>(&h);
}

__device__ __forceinline__ unsigned short f2bf(float f) {
    unsigned u = __float_as_uint(f);
    return (unsigned short)((u + 0x7FFFu + ((u >> 16) & 1u)) >> 16);   // RNE
}

__global__ __launch_bounds__(256) void conv3x3_mfma(
    const float* __restrict__ x,      // [16][8][1024][1024]
    const float* __restrict__ wgt,    // [8][8][3][3]
    const float* __restrict__ bias,   // [8]
    float* __restrict__ out)          // [16][8][1024][1024]
{
    __shared__ int4 lds[SROWS * UROW];

    const int tid  = threadIdx.x;
    const int lane = tid & 63;
    const int wv   = tid >> 6;        // wave 0..3
    const int l15  = lane & 15;
    const int ch   = lane >> 4;       // k-chunk / store-row-chunk

    // ---- XCD chunk swizzle: 18432 blocks = 8 XCDs x 2304 contiguous ----
    const unsigned bid  = blockIdx.x;
    const unsigned work = (bid & 7u) * (NBLK / 8u) + (bid >> 3);
    const int wz = (int)(work / (GX * GY));            // n
    const unsigned r1 = work - (unsigned)wz * (GX * GY);
    const int wy = (int)(r1 / GX);                     // h block
    const int wx = (int)(r1 - (unsigned)wy * GX);      // w block

    const int h0 = wy * HB;
    const int w0 = (wx == GX - 1) ? (WW - WB) : wx * WB;   // 900 or wx*124, mult of 4

    const float* xn = x + (size_t)wz * 8 * HW;

    // ---- per-lane tap -> (kh,kw) LDS offsets (int4 units); +3 = stage shift ----
    const int t0  = ch;                       // taps 0..3   (MFMA 0)
    const int kh0 = (t0 >= 3) ? 1 : 0;
    const int kw0 = t0 - 3 * kh0;
    const int t1  = 4 + ch;                   // taps 4..7   (MFMA 1)
    const int kh1 = (t1 >= 6) ? 2 : 1;
    const int kw1 = t1 - 3 * kh1;
    const int off0 = kh0 * UROW + kw0 + 3;
    const int off1 = kh1 * UROW + kw1 + 3;
    const int off2 = 2 * UROW + 2 + 3;        // tap 8 (2,2), uniform

    // ---- weight B-fragments: lane l -> col co=l15, k=(ch*8+j) -> tap,ci=j ----
    const int  coc = (l15 < 8) ? l15 : 7;
    const bool com = (l15 < 8);
    short8 b0, b1, b2;
    {
        const float* wp0 = wgt + coc * 72 + kh0 * 3 + kw0;   // + ci*9
        const float* wp1 = wgt + coc * 72 + kh1 * 3 + kw1;
        const float* wp2 = wgt + coc * 72 + 2 * 3 + 2;
#pragma unroll
        for (int j = 0; j < 8; ++j) {
            b0[j] = (short)(com ? f2bf(wp0[j * 9]) : 0);
            b1[j] = (short)(com ? f2bf(wp1[j * 9]) : 0);
            b2[j] = (short)((com && ch == 0) ? f2bf(wp2[j * 9]) : 0);  // taps 9..11 = 0
        }
    }
    const float bv = com ? bias[l15] : 0.0f;

    // ---- stage: (4w x 8ci) tiles; 8 dwordx4 loads, 16 cvt_pk, 4 b128 writes ----
    for (int t = tid; t < NTILES; t += 256) {
        const int row = t / TPR;
        const int wt4 = t - row * TPR;
        const int gh  = h0 - 1 + row;
        const int gw0 = w0 - 4 + wt4 * 4;     // mult of 4 -> whole-tile validity
        const bool ok = ((unsigned)gh < (unsigned)HH) && ((unsigned)gw0 < (unsigned)WW);

        f32x4 v0, v1, v2, v3, v4, v5, v6, v7;
        if (ok) {
            const float* p = xn + (size_t)gh * WW + gw0;
            v0 = *reinterpret_cast<const f32x4*>(p + 0 * (size_t)HW);
            v1 = *reinterpret_cast<const f32x4*>(p + 1 * (size_t)HW);
            v2 = *reinterpret_cast<const f32x4*>(p + 2 * (size_t)HW);
            v3 = *reinterpret_cast<const f32x4*>(p + 3 * (size_t)HW);
            v4 = *reinterpret_cast<const f32x4*>(p + 4 * (size_t)HW);
            v5 = *reinterpret_cast<const f32x4*>(p + 5 * (size_t)HW);
            v6 = *reinterpret_cast<const f32x4*>(p + 6 * (size_t)HW);
            v7 = *reinterpret_cast<const f32x4*>(p + 7 * (size_t)HW);
        } else {
            v0 = v1 = v2 = v3 = v4 = v5 = v6 = v7 = (f32x4)0.0f;
        }

        int4* dst = &lds[row * UROW + wt4 * 4];
#pragma unroll
        for (int q = 0; q < 4; ++q) {
            int4 pk;
            pk.x = pk2(v0[q], v1[q]);
            pk.y = pk2(v2[q], v3[q]);
            pk.z = pk2(v4[q], v5[q]);
            pk.w = pk2(v6[q], v7[q]);
            dst[q] = pk;
        }
    }
    __syncthreads();

    // ---- compute: wave owns h-rows 2wv,2wv+1; 8 w-tiles of 16 each ----
    f32x4 acc[2][8];
#pragma unroll
    for (int th = 0; th < 2; ++th)
#pragma unroll
        for (int wt = 0; wt < 8; ++wt) {
            acc[th][wt].x = bv; acc[th][wt].y = bv;
            acc[th][wt].z = bv; acc[th][wt].w = bv;
        }

#pragma unroll
    for (int th = 0; th < 2; ++th) {
        const int hl = wv * 2 + th;
        const int ub = hl * UROW + l15;       // A row m = l15
#pragma unroll
        for (int wt = 0; wt < 8; ++wt) {
            const int u = ub + wt * 16;
            short8 a0 = *reinterpret_cast<const short8*>(&lds[u + off0]);
            short8 a1 = *reinterpret_cast<const short8*>(&lds[u + off1]);
            short8 a2 = *reinterpret_cast<const short8*>(&lds[u + off2]);
            f32x4 c = acc[th][wt];
            c = __builtin_amdgcn_mfma_f32_16x16x32_bf16(a0, b0, c, 0, 0, 0);
            c = __builtin_amdgcn_mfma_f32_16x16x32_bf16(a1, b1, c, 0, 0, 0);
            c = __builtin_amdgcn_mfma_f32_16x16x32_bf16(a2, b2, c, 0, 0, 0);
            acc[th][wt] = c;
        }
    }

    // ---- store: lane (co=l15<8) holds D rows m=wt*16+ch*4+r -> float4 ----
    if (com) {
#pragma unroll
        for (int th = 0; th < 2; ++th) {
            const int hl = wv * 2 + th;
            float* op = out + ((size_t)wz * 8 + l15) * HW
                            + (size_t)(h0 + hl) * WW + w0;
#pragma unroll
            for (int wt = 0; wt < 8; ++wt) {
                if (wt == 7 && ch == 3) continue;   // w_off 124..127 not owned
                *reinterpret_cast<float4*>(op + wt * 16 + ch * 4) =
                    *reinterpret_cast<const float4*>(&acc[th][wt]);
            }
        }
    }
}

extern "C" void kernel_launch(void* const* d_in, const int* in_sizes, int n_in,
                              void* d_out, int out_size, void* d_ws, size_t ws_size,
                              hipStream_t stream) {
    const float* x    = (const float*)d_in[0];
    const float* wgt  = (const float*)d_in[1];
    const float* bias = (const float*)d_in[2];
    float* out = (float*)d_out;

    dim3 grid(NBLK, 1, 1);
    dim3 block(256, 1, 1);
    conv3x3_mfma<<<grid, block, 0, stream>>>(x, wgt, bias, out);
}